// Round 16
// baseline (87.734 us; speedup 1.0000x reference)
//
#include <hip/hip_runtime.h>
#include <hip/hip_bf16.h>

#define CIN  64
#define HH   128
#define WW   128
#define COUT 128
#define HO   126
#define WO   126
#define NB   32
#define HW   (HH * WW)

typedef __bf16 bf16x8 __attribute__((ext_vector_type(8)));
typedef float f32x16 __attribute__((ext_vector_type(16)));

// ws2 granule layout: [step(18)=(s,h)][kg(4)][cout(128)] 16B granules
// granule(step,kg,cout)[j] = bf16(w[cout][ci = 32h + 8kg + j][s])
__global__ void wreorder_3556(const float* __restrict__ w, unsigned short* __restrict__ ws2) {
    int e = blockIdx.x * 256 + threadIdx.x;      // 0..73727
    if (e >= 73728) return;
    int j = e & 7, cout = (e >> 3) & 127, kg = (e >> 10) & 3, h = (e >> 12) & 1, s = e >> 13;
    __bf16 v = (__bf16)w[cout * 576 + (h * 32 + kg * 8 + j) * 9 + s];
    ws2[e] = __builtin_bit_cast(unsigned short, v);
}

// LDS: xs [row(6)][cg(8)][col(130)] 16B granules (ci-major) = 99840 B -> 1 block/CU
#define SMEM_BYTES 99840

__device__ __forceinline__ unsigned lds_addr(const void* p) {
    return (unsigned)(unsigned long long)(const __attribute__((address_space(3))) unsigned char*)p;
}
template<int OFF>
__device__ __forceinline__ bf16x8 ds_read128(unsigned base) {
    bf16x8 d;
    asm volatile("ds_read_b128 %0, %1 offset:%c2" : "=v"(d) : "v"(base), "i"(OFF));
    return d;
}
template<int OFF>
__device__ __forceinline__ bf16x8 glob_load128(const unsigned char* sbase, unsigned voff) {
    bf16x8 d;
    asm volatile("global_load_dwordx4 %0, %1, %2 offset:%c3"
                 : "=v"(d) : "v"(voff), "s"(sbase), "i"(OFF));
    return d;
}

#define MFMA_(a, b, c) __builtin_amdgcn_mfma_f32_32x32x16_bf16((a), (b), (c), 0, 0, 0)

// step T: s = T>>1, h = T&1; kh = s/3, kw = s%3
#define S_(T)  ((T) >> 1)
#define H_(T)  ((T) & 1)
#define KH_(T) (S_(T) / 3)
#define KW_(T) (S_(T) % 3)
#define IMMB(T, KS, N) (KH_(T) * 16640 + (H_(T) * 4 + (KS) * 2) * 2080 + ((N) * 32 + KW_(T)) * 16)

template<bool USE_WS>
__global__ __launch_bounds__(256, 1)
void conv_min_tanh_3556(const float* __restrict__ x, const float* __restrict__ w,
                        const float* __restrict__ bias,
                        const unsigned char* __restrict__ wsr_b,
                        float* __restrict__ out) {
    __shared__ __align__(16) unsigned char smem[SMEM_BYTES];

    // XCD-chunked bijective swizzle (1024 = 8 * 128)
    const int bid = blockIdx.x;
    const int blk = (bid & 7) * 128 + (bid >> 3);
    const int b   = blk >> 5;                 // batch
    const int R   = (blk & 31) * 4;           // output rows R..R+3 (ragged at R=124)

    const int tid  = threadIdx.x;
    const int lane = tid & 63;
    const int wr   = tid >> 6;                // wave's output row within block (0..3)
    const int l31 = lane & 31;
    const int l5  = lane >> 5;

    // ---- stage x rows R..R+5 (clamped) into xs[row][cg][col] granules (conflict-free)
    {
        const int cg = tid >> 5, c0 = tid & 31;
        const float* xb0 = x + (size_t)b * CIN * HW + (size_t)(cg * 8) * HW;
        #pragma unroll
        for (int row = 0; row < 6; ++row) {
            int rr = R + row; if (rr > 127) rr = 127;   // clamp: garbage only for discarded rows
            #pragma unroll
            for (int i = 0; i < 4; ++i) {
                const float* src = xb0 + (size_t)rr * WW + i * 32 + c0;
                union { unsigned short us[8]; int4 i4; } p;
                #pragma unroll
                for (int j = 0; j < 8; ++j) {
                    __bf16 t = (__bf16)src[(size_t)j * HW];
                    p.us[j] = __builtin_bit_cast(unsigned short, t);
                }
                *(int4*)(smem + ((row * 8 + cg) * 130 + i * 32 + c0) * 16) = p.i4;
            }
        }
        if (tid < 96) {   // zero-pad cols 128,129 for 6 rows
            int row = tid / 16, cgz = (tid >> 1) & 7, colz = 128 + (tid & 1);
            int4 z = {0, 0, 0, 0};
            *(int4*)(smem + ((row * 8 + cgz) * 130 + colz) * 16) = z;
        }
    }
    __syncthreads();

    f32x16 acc[4][4] = {};   // [m][n] : 128 cout x 128 col (one row per wave)

    if constexpr (USE_WS) {
        const unsigned baseB = lds_addr(smem) + (unsigned)(wr * 16640 + l5 * 2080 + l31 * 16);
        const unsigned voffA = (unsigned)(l5 * 2048 + l31 * 16);

        bf16x8 A2[2][2][4];   // [slot][ks][m]  64 VGPR
        bf16x8 B2[2][2][4];   // [slot][ks][n]  64 VGPR

        #define PRELA(T) do {                                                                 \
            const unsigned _va = voffA + (T) * 8192u, _vb = _va + 4096u;                      \
            A2[(T) & 1][0][0] = glob_load128<0>(wsr_b, _va);                                  \
            A2[(T) & 1][0][1] = glob_load128<512>(wsr_b, _va);                                \
            A2[(T) & 1][0][2] = glob_load128<1024>(wsr_b, _va);                               \
            A2[(T) & 1][0][3] = glob_load128<1536>(wsr_b, _va);                               \
            A2[(T) & 1][1][0] = glob_load128<0>(wsr_b, _vb);                                  \
            A2[(T) & 1][1][1] = glob_load128<512>(wsr_b, _vb);                                \
            A2[(T) & 1][1][2] = glob_load128<1024>(wsr_b, _vb);                               \
            A2[(T) & 1][1][3] = glob_load128<1536>(wsr_b, _vb); } while (0)

        #define PRELB(T) do {                                                                 \
            B2[(T) & 1][0][0] = ds_read128<IMMB(T,0,0)>(baseB);                               \
            B2[(T) & 1][0][1] = ds_read128<IMMB(T,0,1)>(baseB);                               \
            B2[(T) & 1][0][2] = ds_read128<IMMB(T,0,2)>(baseB);                               \
            B2[(T) & 1][0][3] = ds_read128<IMMB(T,0,3)>(baseB);                               \
            B2[(T) & 1][1][0] = ds_read128<IMMB(T,1,0)>(baseB);                               \
            B2[(T) & 1][1][1] = ds_read128<IMMB(T,1,1)>(baseB);                               \
            B2[(T) & 1][1][2] = ds_read128<IMMB(T,1,2)>(baseB);                               \
            B2[(T) & 1][1][3] = ds_read128<IMMB(T,1,3)>(baseB); } while (0)

        #define KSTEP(T) do {                                                                 \
            if ((T) <= 16) asm volatile("s_waitcnt lgkmcnt(8) vmcnt(8)" ::: "memory");        \
            else           asm volatile("s_waitcnt lgkmcnt(0) vmcnt(0)" ::: "memory");        \
            __builtin_amdgcn_sched_barrier(0);                                                \
            __builtin_amdgcn_s_setprio(1);                                                    \
            { const int _q = (T) & 1;                                                         \
              _Pragma("unroll")                                                               \
              for (int _ks = 0; _ks < 2; ++_ks)                                               \
                _Pragma("unroll")                                                             \
                for (int _m = 0; _m < 4; ++_m)                                                \
                  _Pragma("unroll")                                                           \
                  for (int _n = 0; _n < 4; ++_n)                                              \
                    acc[_m][_n] = MFMA_(A2[_q][_ks][_m], B2[_q][_ks][_n], acc[_m][_n]); }     \
            __builtin_amdgcn_s_setprio(0);                                                    \
            __builtin_amdgcn_sched_barrier(0);                                                \
            if ((T) + 2 <= 17) { PRELB((T) + 2); PRELA((T) + 2); }                            \
        } while (0)

        PRELA(0); PRELB(0); PRELA(1); PRELB(1);

        KSTEP(0);  KSTEP(1);  KSTEP(2);  KSTEP(3);  KSTEP(4);  KSTEP(5);
        KSTEP(6);  KSTEP(7);  KSTEP(8);  KSTEP(9);  KSTEP(10); KSTEP(11);
        KSTEP(12); KSTEP(13); KSTEP(14); KSTEP(15); KSTEP(16); KSTEP(17);

        asm volatile("s_waitcnt lgkmcnt(0) vmcnt(0)" ::: "memory");
        __builtin_amdgcn_sched_barrier(0);
    } else {
        // fallback: plain loop straight from w (same fat-tile geometry)
        #pragma unroll
        for (int step = 0; step < 18; ++step) {
            const int s = step >> 1, h = step & 1;
            const int kh = s / 3, kw = s % 3;
            bf16x8 A[2][4], B[2][4];
            #pragma unroll
            for (int ks = 0; ks < 2; ++ks) {
                #pragma unroll
                for (int m = 0; m < 4; ++m)
                    #pragma unroll
                    for (int j = 0; j < 8; ++j)
                        A[ks][m][j] = (__bf16)w[(m * 32 + l31) * 576 +
                                                (h * 32 + (2 * ks + l5) * 8 + j) * 9 + s];
                const int rowOff = ((wr + kh) * 8 + h * 4 + ks * 2 + l5) * 2080;
                #pragma unroll
                for (int n = 0; n < 4; ++n)
                    B[ks][n] = *(const bf16x8*)(smem + rowOff + (n * 32 + l31 + kw) * 16);
            }
            #pragma unroll
            for (int ks = 0; ks < 2; ++ks)
                #pragma unroll
                for (int m = 0; m < 4; ++m)
                    #pragma unroll
                    for (int n = 0; n < 4; ++n)
                        acc[m][n] = MFMA_(A[ks][m], B[ks][n], acc[m][n]);
        }
    }

    // ---- epilogue: +bias, min over ALL 128 couts in-wave, tanh(tanh), direct store
    {
        float pm[4] = {1e30f, 1e30f, 1e30f, 1e30f};
        #pragma unroll
        for (int m = 0; m < 4; ++m) {
            #pragma unroll
            for (int r = 0; r < 16; ++r) {
                float bv = bias[m * 32 + (r & 3) + 8 * (r >> 2) + 4 * l5];
                #pragma unroll
                for (int n = 0; n < 4; ++n)
                    pm[n] = fminf(pm[n], acc[m][n][r] + bv);
            }
        }
        #pragma unroll
        for (int n = 0; n < 4; ++n)
            pm[n] = fminf(pm[n], __shfl_xor(pm[n], 32, 64));

        const int orow = R + wr;
        if (l5 == 0 && orow < HO) {
            #pragma unroll
            for (int n = 0; n < 4; ++n) {
                int col = n * 32 + l31;
                if (col < WO) {
                    float v = tanhf(tanhf(pm[n]));
                    out[((size_t)b * HO + orow) * WO + col] = v;
                }
            }
        }
    }
}

extern "C" void kernel_launch(void* const* d_in, const int* in_sizes, int n_in,
                              void* d_out, int out_size, void* d_ws, size_t ws_size,
                              hipStream_t stream) {
    const float* x    = (const float*)d_in[0];
    const float* w    = (const float*)d_in[1];
    const float* bias = (const float*)d_in[2];
    float* out = (float*)d_out;

    const size_t ws_needed = (size_t)18 * 4 * 128 * 16;   // 147456 B
    if (ws_size >= ws_needed) {
        unsigned short* wsb = (unsigned short*)d_ws;
        wreorder_3556<<<288, 256, 0, stream>>>(w, wsb);
        conv_min_tanh_3556<true><<<NB * 32, 256, 0, stream>>>(x, w, bias, (const unsigned char*)wsb, out);
    } else {
        conv_min_tanh_3556<false><<<NB * 32, 256, 0, stream>>>(x, w, bias, nullptr, out);
    }
}

// Round 17
// 71.902 us; speedup vs baseline: 1.2202x; 1.2202x over previous
//
#include <hip/hip_runtime.h>
#include <hip/hip_bf16.h>

#define CIN  64
#define HH   128
#define WW   128
#define COUT 128
#define HO   126
#define WO   126
#define NB   32
#define HW   (HH * WW)

typedef __bf16 bf16x8 __attribute__((ext_vector_type(8)));
typedef float f32x4 __attribute__((ext_vector_type(4)));

// ws2 granule layout: [step(18)=(s,h)][kg(4)][cout(128)] 16B granules
// granule(step,kg,cout)[j] = bf16(w[cout][ci = 32h + 8kg + j][s])
__global__ void wreorder_3556(const float* __restrict__ w, unsigned short* __restrict__ ws2) {
    int e = blockIdx.x * 256 + threadIdx.x;      // 0..73727
    if (e >= 73728) return;
    int j = e & 7, cout = (e >> 3) & 127, kg = (e >> 10) & 3, h = (e >> 12) & 1, s = e >> 13;
    __bf16 v = (__bf16)w[cout * 576 + (h * 32 + kg * 8 + j) * 9 + s];
    ws2[e] = __builtin_bit_cast(unsigned short, v);
}

// LDS: xs [row(4)][cg(8)][col(130)] 16B granules (ci-major) = 66560 B -> 2 blocks/CU
#define SMEM_BYTES 66560

__device__ __forceinline__ unsigned lds_addr(const void* p) {
    return (unsigned)(unsigned long long)(const __attribute__((address_space(3))) unsigned char*)p;
}
template<int OFF>
__device__ __forceinline__ bf16x8 ds_read128(unsigned base) {
    bf16x8 d;
    asm volatile("ds_read_b128 %0, %1 offset:%c2" : "=v"(d) : "v"(base), "i"(OFF));
    return d;
}
template<int OFF>
__device__ __forceinline__ bf16x8 glob_load128(const unsigned char* sbase, unsigned voff) {
    bf16x8 d;
    asm volatile("global_load_dwordx4 %0, %1, %2 offset:%c3"
                 : "=v"(d) : "v"(voff), "s"(sbase), "i"(OFF));
    return d;
}

#define MFMA16_(a, b, c) __builtin_amdgcn_mfma_f32_16x16x32_bf16((a), (b), (c), 0, 0, 0)

// step T: s = T>>1, h = T&1; kh = s/3, kw = s%3
#define S_(T)  ((T) >> 1)
#define H_(T)  ((T) & 1)
#define KH_(T) (S_(T) / 3)
#define KW_(T) (S_(T) % 3)
// B addr = baseB + kh*16640 + h*8320 + (n*16 + kw)*16
#define IMMB(T, N) (KH_(T) * 16640 + H_(T) * 8320 + ((N) * 16 + KW_(T)) * 16)

template<bool USE_WS>
__global__ __launch_bounds__(256, 2)
void conv_min_tanh_3556(const float* __restrict__ x, const float* __restrict__ w,
                        const float* __restrict__ bias,
                        const unsigned char* __restrict__ wsr_b,
                        float* __restrict__ out) {
    __shared__ __align__(16) unsigned char smem[SMEM_BYTES];

    // XCD-chunked bijective swizzle (2016 = 8 * 252)
    const int bid = blockIdx.x;
    const int blk = (bid & 7) * 252 + (bid >> 3);
    const int b   = blk / 63;
    const int R   = (blk - b * 63) * 2;      // output rows R, R+1; input rows R..R+3

    const int tid  = threadIdx.x;
    const int lane = tid & 63;
    const int wid  = tid >> 6;               // 0..3
    const int l15 = lane & 15;
    const int lg  = lane >> 4;               // 0..3 (16-lane group)
    const int waveC = wid & 1;               // col half (0/1)
    const int waveR = wid >> 1;              // output row within pair (0/1)

    // ---- stage x rows R..R+3 into xs[row][cg][col] granules (conflict-free, R13 pattern)
    {
        const int cg = tid >> 5, c0 = tid & 31;
        const float* xb = x + (size_t)b * CIN * HW + (size_t)(cg * 8) * HW + (size_t)R * WW + c0;
        #pragma unroll
        for (int row = 0; row < 4; ++row) {
            #pragma unroll
            for (int i = 0; i < 4; ++i) {
                union { unsigned short us[8]; int4 i4; } p;
                #pragma unroll
                for (int j = 0; j < 8; ++j) {
                    __bf16 t = (__bf16)xb[(size_t)j * HW + (size_t)row * WW + i * 32];
                    p.us[j] = __builtin_bit_cast(unsigned short, t);
                }
                *(int4*)(smem + ((row * 8 + cg) * 130 + i * 32 + c0) * 16) = p.i4;
            }
        }
        if (tid < 64) {   // zero-pad cols 128,129 for all 4 rows
            int row = tid >> 4, cgz = (tid >> 1) & 7, colz = 128 + (tid & 1);
            int4 z = {0, 0, 0, 0};
            *(int4*)(smem + ((row * 8 + cgz) * 130 + colz) * 16) = z;
        }
    }
    __syncthreads();

    f32x4 acc[8][4] = {};   // [m][n] : 128 cout x 64 col, 16x16 tiles

    if constexpr (USE_WS) {
        // B base: row = waveR (+kh via imm), granule g = lg (+4h via imm), col = waveC*64 + n*16 + l15 (+kw imm)
        const unsigned baseB = lds_addr(smem) +
            (unsigned)(waveR * 16640 + lg * 2080 + (waveC * 64 + l15) * 16);
        // A base: granule(step, kg = lg, cout = m*16 + l15); frag offset m*256
        const unsigned voffA = (unsigned)(lg * 2048 + l15 * 16);

        bf16x8 A2[2][8];   // [slot][m]  64 VGPR
        bf16x8 B2[2][4];   // [slot][n]  32 VGPR

        #define PRELA(T) do { const unsigned _va = voffA + (T) * 8192u;                       \
            A2[(T) & 1][0] = glob_load128<0>(wsr_b, _va);                                     \
            A2[(T) & 1][1] = glob_load128<256>(wsr_b, _va);                                   \
            A2[(T) & 1][2] = glob_load128<512>(wsr_b, _va);                                   \
            A2[(T) & 1][3] = glob_load128<768>(wsr_b, _va);                                   \
            A2[(T) & 1][4] = glob_load128<1024>(wsr_b, _va);                                  \
            A2[(T) & 1][5] = glob_load128<1280>(wsr_b, _va);                                  \
            A2[(T) & 1][6] = glob_load128<1536>(wsr_b, _va);                                  \
            A2[(T) & 1][7] = glob_load128<1792>(wsr_b, _va); } while (0)

        #define PRELB(T) do {                                                                 \
            B2[(T) & 1][0] = ds_read128<IMMB(T,0)>(baseB);                                    \
            B2[(T) & 1][1] = ds_read128<IMMB(T,1)>(baseB);                                    \
            B2[(T) & 1][2] = ds_read128<IMMB(T,2)>(baseB);                                    \
            B2[(T) & 1][3] = ds_read128<IMMB(T,3)>(baseB); } while (0)

        #define KSTEP(T) do {                                                                 \
            if ((T) <= 16) asm volatile("s_waitcnt lgkmcnt(4) vmcnt(8)" ::: "memory");        \
            else           asm volatile("s_waitcnt lgkmcnt(0) vmcnt(0)" ::: "memory");        \
            __builtin_amdgcn_sched_barrier(0);                                                \
            __builtin_amdgcn_s_setprio(1);                                                    \
            { const int _q = (T) & 1;                                                         \
              _Pragma("unroll")                                                               \
              for (int _m = 0; _m < 8; ++_m)                                                  \
                _Pragma("unroll")                                                             \
                for (int _n = 0; _n < 4; ++_n)                                                \
                    acc[_m][_n] = MFMA16_(A2[_q][_m], B2[_q][_n], acc[_m][_n]); }             \
            __builtin_amdgcn_s_setprio(0);                                                    \
            __builtin_amdgcn_sched_barrier(0);                                                \
            if ((T) + 2 <= 17) { PRELB((T) + 2); PRELA((T) + 2); }                            \
        } while (0)

        PRELA(0); PRELB(0); PRELA(1); PRELB(1);

        KSTEP(0);  KSTEP(1);  KSTEP(2);  KSTEP(3);  KSTEP(4);  KSTEP(5);
        KSTEP(6);  KSTEP(7);  KSTEP(8);  KSTEP(9);  KSTEP(10); KSTEP(11);
        KSTEP(12); KSTEP(13); KSTEP(14); KSTEP(15); KSTEP(16); KSTEP(17);

        asm volatile("s_waitcnt lgkmcnt(0) vmcnt(0)" ::: "memory");
        __builtin_amdgcn_sched_barrier(0);
    } else {
        // fallback: plain loop straight from w, same geometry
        #pragma unroll
        for (int step = 0; step < 18; ++step) {
            const int s = step >> 1, h = step & 1;
            const int kh = s / 3, kw = s % 3;
            bf16x8 A[8], B[4];
            #pragma unroll
            for (int m = 0; m < 8; ++m)
                #pragma unroll
                for (int j = 0; j < 8; ++j)
                    A[m][j] = (__bf16)w[(m * 16 + l15) * 576 +
                                        (h * 32 + lg * 8 + j) * 9 + s];
            #pragma unroll
            for (int n = 0; n < 4; ++n)
                B[n] = *(const bf16x8*)(smem + (waveR + kh) * 16640 + h * 8320 + lg * 2080 +
                                        (waveC * 64 + n * 16 + l15 + kw) * 16);
            #pragma unroll
            for (int m = 0; m < 8; ++m)
                #pragma unroll
                for (int n = 0; n < 4; ++n)
                    acc[m][n] = MFMA16_(A[m], B[n], acc[m][n]);
        }
    }

    // ---- epilogue: +bias, min over ALL 128 couts (in-lane 32 + shfl 16/32), tanh(tanh)
    {
        float pm[4] = {1e30f, 1e30f, 1e30f, 1e30f};
        #pragma unroll
        for (int m = 0; m < 8; ++m) {
            #pragma unroll
            for (int r = 0; r < 4; ++r) {
                float bv = bias[m * 16 + lg * 4 + r];    // cout = m*16 + lg*4 + r
                #pragma unroll
                for (int n = 0; n < 4; ++n)
                    pm[n] = fminf(pm[n], acc[m][n][r] + bv);
            }
        }
        #pragma unroll
        for (int n = 0; n < 4; ++n) {
            pm[n] = fminf(pm[n], __shfl_xor(pm[n], 16, 64));
            pm[n] = fminf(pm[n], __shfl_xor(pm[n], 32, 64));
        }
        const int orow = R + waveR;
        if (lg == 0) {
            #pragma unroll
            for (int n = 0; n < 4; ++n) {
                int col = waveC * 64 + n * 16 + l15;
                if (col < WO) {
                    float v = tanhf(tanhf(pm[n]));
                    out[((size_t)b * HO + orow) * WO + col] = v;
                }
            }
        }
    }
}

extern "C" void kernel_launch(void* const* d_in, const int* in_sizes, int n_in,
                              void* d_out, int out_size, void* d_ws, size_t ws_size,
                              hipStream_t stream) {
    const float* x    = (const float*)d_in[0];
    const float* w    = (const float*)d_in[1];
    const float* bias = (const float*)d_in[2];
    float* out = (float*)d_out;

    const size_t ws_needed = (size_t)18 * 4 * 128 * 16;   // 147456 B
    if (ws_size >= ws_needed) {
        unsigned short* wsb = (unsigned short*)d_ws;
        wreorder_3556<<<288, 256, 0, stream>>>(w, wsb);
        conv_min_tanh_3556<true><<<NB * 63, 256, 0, stream>>>(x, w, bias, (const unsigned char*)wsb, out);
    } else {
        conv_min_tanh_3556<false><<<NB * 63, 256, 0, stream>>>(x, w, bias, nullptr, out);
    }
}

// Round 18
// 68.364 us; speedup vs baseline: 1.2833x; 1.0518x over previous
//
#include <hip/hip_runtime.h>
#include <hip/hip_bf16.h>

#define CIN  64
#define HH   128
#define WW   128
#define COUT 128
#define HO   126
#define WO   126
#define NB   32
#define HW   (HH * WW)

typedef __bf16 bf16x8 __attribute__((ext_vector_type(8)));
typedef float f32x4 __attribute__((ext_vector_type(4)));

// ws2 granule layout: [step(18)=(s,h)][kg(4)][cout(128)] 16B granules
// granule(step,kg,cout)[j] = bf16(w[cout][ci = 32h + 8kg + j][s])
__global__ void wreorder_3556(const float* __restrict__ w, unsigned short* __restrict__ ws2) {
    int e = blockIdx.x * 256 + threadIdx.x;      // 0..73727
    if (e >= 73728) return;
    int j = e & 7, cout = (e >> 3) & 127, kg = (e >> 10) & 3, h = (e >> 12) & 1, s = e >> 13;
    __bf16 v = (__bf16)w[cout * 576 + (h * 32 + kg * 8 + j) * 9 + s];
    ws2[e] = __builtin_bit_cast(unsigned short, v);
}

// LDS: xs [row(4)][cg(8)][col(130)] 16B granules (ci-major) = 66560 | pmin[2][2][128] f32
#define PM_OFF  66560
#define SMEM_BYTES (66560 + 2048)   // 68608 -> 2 blocks/CU

__device__ __forceinline__ unsigned lds_addr(const void* p) {
    return (unsigned)(unsigned long long)(const __attribute__((address_space(3))) unsigned char*)p;
}
template<int OFF>
__device__ __forceinline__ bf16x8 ds_read128(unsigned base) {
    bf16x8 d;
    asm volatile("ds_read_b128 %0, %1 offset:%c2" : "=v"(d) : "v"(base), "i"(OFF));
    return d;
}
template<int OFF>
__device__ __forceinline__ bf16x8 glob_load128(const unsigned char* sbase, unsigned voff) {
    bf16x8 d;
    asm volatile("global_load_dwordx4 %0, %1, %2 offset:%c3"
                 : "=v"(d) : "v"(voff), "s"(sbase), "i"(OFF));
    return d;
}

#define MFMA16_(a, b, c) __builtin_amdgcn_mfma_f32_16x16x32_bf16((a), (b), (c), 0, 0, 0)

// step T: s = T>>1, h = T&1; kh = s/3, kw = s%3
#define S_(T)  ((T) >> 1)
#define H_(T)  ((T) & 1)
#define KH_(T) (S_(T) / 3)
#define KW_(T) (S_(T) % 3)
// B addr = baseB + kh*16640 + h*8320 + (n*16 + kw)*16
#define IMMB(T, N) (KH_(T) * 16640 + H_(T) * 8320 + ((N) * 16 + KW_(T)) * 16)

template<bool USE_WS>
__global__ __launch_bounds__(256, 2)
void conv_min_tanh_3556(const float* __restrict__ x, const float* __restrict__ w,
                        const float* __restrict__ bias,
                        const unsigned char* __restrict__ wsr_b,
                        float* __restrict__ out) {
    __shared__ __align__(16) unsigned char smem[SMEM_BYTES];
    float* pmin = (float*)(smem + PM_OFF);

    // XCD-chunked bijective swizzle (2016 = 8 * 252)
    const int bid = blockIdx.x;
    const int blk = (bid & 7) * 252 + (bid >> 3);
    const int b   = blk / 63;
    const int R   = (blk - b * 63) * 2;      // output rows R, R+1; input rows R..R+3

    const int tid  = threadIdx.x;
    const int lane = tid & 63;
    const int wid  = tid >> 6;               // 0..3
    const int l15 = lane & 15;
    const int lg  = lane >> 4;               // 0..3 (16-lane group)
    const int waveM = wid & 1;               // cout half (0/1)
    const int waveR = wid >> 1;              // output row within pair (0/1)
    const int mb = waveM * 64;

    // ---- stage x rows R..R+3 into xs[row][cg][col] granules (conflict-free scalar pattern)
    {
        const int cg = tid >> 5, c0 = tid & 31;
        const float* xb = x + (size_t)b * CIN * HW + (size_t)(cg * 8) * HW + (size_t)R * WW + c0;
        #pragma unroll
        for (int row = 0; row < 4; ++row) {
            #pragma unroll
            for (int i = 0; i < 4; ++i) {
                union { unsigned short us[8]; int4 i4; } p;
                #pragma unroll
                for (int j = 0; j < 8; ++j) {
                    __bf16 t = (__bf16)xb[(size_t)j * HW + (size_t)row * WW + i * 32];
                    p.us[j] = __builtin_bit_cast(unsigned short, t);
                }
                *(int4*)(smem + ((row * 8 + cg) * 130 + i * 32 + c0) * 16) = p.i4;
            }
        }
        if (tid < 64) {   // zero-pad cols 128,129 for all 4 rows
            int row = tid >> 4, cgz = (tid >> 1) & 7, colz = 128 + (tid & 1);
            int4 z = {0, 0, 0, 0};
            *(int4*)(smem + ((row * 8 + cgz) * 130 + colz) * 16) = z;
        }
    }
    __syncthreads();

    f32x4 acc[4][8] = {};   // [m][n] : 64 cout x 128 col, 16x16 tiles

    if constexpr (USE_WS) {
        // B base: row = waveR (+kh imm), granule cg = lg (+4h imm), col = n*16 + l15 (+kw imm)
        const unsigned baseB = lds_addr(smem) +
            (unsigned)(waveR * 16640 + lg * 2080 + l15 * 16);
        // A: granule(step, kg = lg, cout = mb + m*16 + l15); m offset = m*256
        const unsigned voffA = (unsigned)(lg * 2048 + (mb + l15) * 16);

        bf16x8 A2[2][4];   // [slot][m]  32 VGPR
        bf16x8 B2[2][8];   // [slot][n]  64 VGPR

        #define PRELA(T) do { const unsigned _va = voffA + (T) * 8192u;                       \
            A2[(T) & 1][0] = glob_load128<0>(wsr_b, _va);                                     \
            A2[(T) & 1][1] = glob_load128<256>(wsr_b, _va);                                   \
            A2[(T) & 1][2] = glob_load128<512>(wsr_b, _va);                                   \
            A2[(T) & 1][3] = glob_load128<768>(wsr_b, _va); } while (0)

        #define PRELB(T) do {                                                                 \
            B2[(T) & 1][0] = ds_read128<IMMB(T,0)>(baseB);                                    \
            B2[(T) & 1][1] = ds_read128<IMMB(T,1)>(baseB);                                    \
            B2[(T) & 1][2] = ds_read128<IMMB(T,2)>(baseB);                                    \
            B2[(T) & 1][3] = ds_read128<IMMB(T,3)>(baseB);                                    \
            B2[(T) & 1][4] = ds_read128<IMMB(T,4)>(baseB);                                    \
            B2[(T) & 1][5] = ds_read128<IMMB(T,5)>(baseB);                                    \
            B2[(T) & 1][6] = ds_read128<IMMB(T,6)>(baseB);                                    \
            B2[(T) & 1][7] = ds_read128<IMMB(T,7)>(baseB); } while (0)

        #define KSTEP(T) do {                                                                 \
            if ((T) <= 16) asm volatile("s_waitcnt lgkmcnt(8) vmcnt(4)" ::: "memory");        \
            else           asm volatile("s_waitcnt lgkmcnt(0) vmcnt(0)" ::: "memory");        \
            __builtin_amdgcn_sched_barrier(0);                                                \
            __builtin_amdgcn_s_setprio(1);                                                    \
            { const int _q = (T) & 1;                                                         \
              _Pragma("unroll")                                                               \
              for (int _m = 0; _m < 4; ++_m)                                                  \
                _Pragma("unroll")                                                             \
                for (int _n = 0; _n < 8; ++_n)                                                \
                    acc[_m][_n] = MFMA16_(A2[_q][_m], B2[_q][_n], acc[_m][_n]); }             \
            __builtin_amdgcn_s_setprio(0);                                                    \
            __builtin_amdgcn_sched_barrier(0);                                                \
            if ((T) + 2 <= 17) { PRELB((T) + 2); PRELA((T) + 2); }                            \
        } while (0)

        PRELA(0); PRELB(0); PRELA(1); PRELB(1);

        KSTEP(0);  KSTEP(1);  KSTEP(2);  KSTEP(3);  KSTEP(4);  KSTEP(5);
        KSTEP(6);  KSTEP(7);  KSTEP(8);  KSTEP(9);  KSTEP(10); KSTEP(11);
        KSTEP(12); KSTEP(13); KSTEP(14); KSTEP(15); KSTEP(16); KSTEP(17);

        asm volatile("s_waitcnt lgkmcnt(0) vmcnt(0)" ::: "memory");
        __builtin_amdgcn_sched_barrier(0);
    } else {
        // fallback: plain loop straight from w, same geometry
        #pragma unroll
        for (int step = 0; step < 18; ++step) {
            const int s = step >> 1, h = step & 1;
            const int kh = s / 3, kw = s % 3;
            bf16x8 A[4], B[8];
            #pragma unroll
            for (int m = 0; m < 4; ++m)
                #pragma unroll
                for (int j = 0; j < 8; ++j)
                    A[m][j] = (__bf16)w[(mb + m * 16 + l15) * 576 +
                                        (h * 32 + lg * 8 + j) * 9 + s];
            #pragma unroll
            for (int n = 0; n < 8; ++n)
                B[n] = *(const bf16x8*)(smem + (waveR + kh) * 16640 + h * 8320 + lg * 2080 +
                                        (n * 16 + l15 + kw) * 16);
            #pragma unroll
            for (int m = 0; m < 4; ++m)
                #pragma unroll
                for (int n = 0; n < 8; ++n)
                    acc[m][n] = MFMA16_(A[m], B[n], acc[m][n]);
        }
    }

    // ---- epilogue: +bias, min over this wave's 64 couts, shfl, cross-waveM via pmin
    {
        float pm[8];
        #pragma unroll
        for (int n = 0; n < 8; ++n) pm[n] = 1e30f;
        #pragma unroll
        for (int m = 0; m < 4; ++m) {
            #pragma unroll
            for (int r = 0; r < 4; ++r) {
                float bv = bias[mb + m * 16 + lg * 4 + r];    // cout
                #pragma unroll
                for (int n = 0; n < 8; ++n)
                    pm[n] = fminf(pm[n], acc[m][n][r] + bv);
            }
        }
        #pragma unroll
        for (int n = 0; n < 8; ++n) {
            pm[n] = fminf(pm[n], __shfl_xor(pm[n], 16, 64));
            pm[n] = fminf(pm[n], __shfl_xor(pm[n], 32, 64));
        }
        if (lg == 0) {
            #pragma unroll
            for (int n = 0; n < 8; ++n)
                pmin[(waveR * 2 + waveM) * 128 + n * 16 + l15] = pm[n];
        }
    }
    __syncthreads();
    {
        const int hh  = tid >> 7;            // 0..1
        const int col = tid & 127;
        if (col < WO) {
            float v = fminf(pmin[(hh * 2 + 0) * 128 + col], pmin[(hh * 2 + 1) * 128 + col]);
            v = tanhf(tanhf(v));
            out[((size_t)b * HO + R + hh) * WO + col] = v;
        }
    }
}

extern "C" void kernel_launch(void* const* d_in, const int* in_sizes, int n_in,
                              void* d_out, int out_size, void* d_ws, size_t ws_size,
                              hipStream_t stream) {
    const float* x    = (const float*)d_in[0];
    const float* w    = (const float*)d_in[1];
    const float* bias = (const float*)d_in[2];
    float* out = (float*)d_out;

    const size_t ws_needed = (size_t)18 * 4 * 128 * 16;   // 147456 B
    if (ws_size >= ws_needed) {
        unsigned short* wsb = (unsigned short*)d_ws;
        wreorder_3556<<<288, 256, 0, stream>>>(w, wsb);
        conv_min_tanh_3556<true><<<NB * 63, 256, 0, stream>>>(x, w, bias, (const unsigned char*)wsb, out);
    } else {
        conv_min_tanh_3556<false><<<NB * 63, 256, 0, stream>>>(x, w, bias, nullptr, out);
    }
}

// Round 19
// 68.231 us; speedup vs baseline: 1.2858x; 1.0019x over previous
//
#include <hip/hip_runtime.h>
#include <hip/hip_bf16.h>

#define CIN  64
#define HH   128
#define WW   128
#define COUT 128
#define HO   126
#define WO   126
#define NB   32
#define HW   (HH * WW)

typedef __bf16 bf16x8 __attribute__((ext_vector_type(8)));
typedef float f32x4 __attribute__((ext_vector_type(4)));

// ws2 granule layout: [step(18)=(s,h)][kg(4)][cout(128)] 16B granules
// granule(step,kg,cout)[j] = bf16(w[cout][ci = 32h + 8kg + j][s])
__global__ void wreorder_3556(const float* __restrict__ w, unsigned short* __restrict__ ws2) {
    int e = blockIdx.x * 256 + threadIdx.x;      // 0..73727
    if (e >= 73728) return;
    int j = e & 7, cout = (e >> 3) & 127, kg = (e >> 10) & 3, h = (e >> 12) & 1, s = e >> 13;
    __bf16 v = (__bf16)w[cout * 576 + (h * 32 + kg * 8 + j) * 9 + s];
    ws2[e] = __builtin_bit_cast(unsigned short, v);
}

// LDS x layout: [row(4)][h(2)][colblk(9)][kg(4)][c(16)] 16B granules, block stride 1040B (16B pad)
//   addr(row,h,col,kg) = row*18720 + h*9360 + (col>>4)*1040 + kg*256 + (col&15)*16
// B wave-read (row,h,kg=lg fixed per lane-group, col = n*16 + l15 + kw) = fully lane-contiguous.
#define ROW_STRIDE 18720
#define H_STRIDE   9360
#define BLK_STRIDE 1040
#define PM_OFF  74880
#define SMEM_BYTES (74880 + 2048)   // 76928 -> 2 blocks/CU

__device__ __forceinline__ unsigned lds_addr(const void* p) {
    return (unsigned)(unsigned long long)(const __attribute__((address_space(3))) unsigned char*)p;
}
template<int OFF>
__device__ __forceinline__ bf16x8 ds_read128(unsigned base) {
    bf16x8 d;
    asm volatile("ds_read_b128 %0, %1 offset:%c2" : "=v"(d) : "v"(base), "i"(OFF));
    return d;
}
template<int OFF>
__device__ __forceinline__ bf16x8 glob_load128(const unsigned char* sbase, unsigned voff) {
    bf16x8 d;
    asm volatile("global_load_dwordx4 %0, %1, %2 offset:%c3"
                 : "=v"(d) : "v"(voff), "s"(sbase), "i"(OFF));
    return d;
}

#define MFMA16_(a, b, c) __builtin_amdgcn_mfma_f32_16x16x32_bf16((a), (b), (c), 0, 0, 0)

// step T: s = T>>1, h = T&1; kh = s/3, kw = s%3
#define S_(T)  ((T) >> 1)
#define H_(T)  ((T) & 1)
#define KH_(T) (S_(T) / 3)
#define KW_(T) (S_(T) % 3)
// B imm = kh*ROW_STRIDE + h*H_STRIDE + n*BLK_STRIDE (base reg holds waveR/lg/lane-col/carry)
#define IMMB(T, N) (KH_(T) * ROW_STRIDE + H_(T) * H_STRIDE + (N) * BLK_STRIDE)

template<bool USE_WS>
__global__ __launch_bounds__(256, 2)
void conv_min_tanh_3556(const float* __restrict__ x, const float* __restrict__ w,
                        const float* __restrict__ bias,
                        const unsigned char* __restrict__ wsr_b,
                        float* __restrict__ out) {
    __shared__ __align__(16) unsigned char smem[SMEM_BYTES];
    float* pmin = (float*)(smem + PM_OFF);

    // XCD-chunked bijective swizzle (2016 = 8 * 252)
    const int bid = blockIdx.x;
    const int blk = (bid & 7) * 252 + (bid >> 3);
    const int b   = blk / 63;
    const int R   = (blk - b * 63) * 2;      // output rows R, R+1; input rows R..R+3

    const int tid  = threadIdx.x;
    const int lane = tid & 63;
    const int wid  = tid >> 6;               // 0..3
    const int l15 = lane & 15;
    const int lg  = lane >> 4;               // 0..3 (16-lane group)
    const int waveM = wid & 1;               // cout half (0/1)
    const int waveR = wid >> 1;              // output row within pair (0/1)
    const int mb = waveM * 64;

    // ---- stage x rows R..R+3 into the block-16-col layout
    {
        const int cg = tid >> 5, c0 = tid & 31;          // cg: ci-granule 0..7; h=cg>>2, kg=cg&3
        const int wbase = (cg >> 2) * H_STRIDE + (cg & 3) * 256 + (c0 & 15) * 16 + (c0 >> 4) * BLK_STRIDE;
        const float* xb = x + (size_t)b * CIN * HW + (size_t)(cg * 8) * HW + (size_t)R * WW + c0;
        #pragma unroll
        for (int row = 0; row < 4; ++row) {
            #pragma unroll
            for (int i = 0; i < 4; ++i) {
                union { unsigned short us[8]; int4 i4; } p;
                #pragma unroll
                for (int j = 0; j < 8; ++j) {
                    __bf16 t = (__bf16)xb[(size_t)j * HW + (size_t)row * WW + i * 32];
                    p.us[j] = __builtin_bit_cast(unsigned short, t);
                }
                *(int4*)(smem + row * ROW_STRIDE + wbase + i * (2 * BLK_STRIDE)) = p.i4;
            }
        }
        if (tid < 64) {   // zero-pad block 8 (cols 128,129) for all rows/h/kg
            int row = tid >> 4, hh = (tid >> 3) & 1, kg = (tid >> 1) & 3, cz = tid & 1;
            int4 z = {0, 0, 0, 0};
            *(int4*)(smem + row * ROW_STRIDE + hh * H_STRIDE + 8 * BLK_STRIDE + kg * 256 + cz * 16) = z;
        }
    }
    __syncthreads();

    f32x4 acc[4][8] = {};   // [m][n] : 64 cout x 128 col, 16x16 tiles

    if constexpr (USE_WS) {
        // B bases per kw: lane col' = l15 + kw; carry into next 16-col block
        unsigned baseB[3];
        #pragma unroll
        for (int kw = 0; kw < 3; ++kw) {
            int cp = l15 + kw;
            baseB[kw] = lds_addr(smem) + (unsigned)(waveR * ROW_STRIDE + lg * 256 +
                        (cp >> 4) * BLK_STRIDE + (cp & 15) * 16);
        }
        // A: granule(step, kg = lg, cout = mb + m*16 + l15); m offset = m*256
        const unsigned voffA = (unsigned)(lg * 2048 + (mb + l15) * 16);

        bf16x8 A2[2][4];   // [slot][m]  32 VGPR
        bf16x8 B2[2][8];   // [slot][n]  64 VGPR

        #define PRELA(T) do { const unsigned _va = voffA + (T) * 8192u;                       \
            A2[(T) & 1][0] = glob_load128<0>(wsr_b, _va);                                     \
            A2[(T) & 1][1] = glob_load128<256>(wsr_b, _va);                                   \
            A2[(T) & 1][2] = glob_load128<512>(wsr_b, _va);                                   \
            A2[(T) & 1][3] = glob_load128<768>(wsr_b, _va); } while (0)

        #define PRELB(T) do { const unsigned _bb = baseB[KW_(T)];                             \
            B2[(T) & 1][0] = ds_read128<IMMB(T,0)>(_bb);                                      \
            B2[(T) & 1][1] = ds_read128<IMMB(T,1)>(_bb);                                      \
            B2[(T) & 1][2] = ds_read128<IMMB(T,2)>(_bb);                                      \
            B2[(T) & 1][3] = ds_read128<IMMB(T,3)>(_bb);                                      \
            B2[(T) & 1][4] = ds_read128<IMMB(T,4)>(_bb);                                      \
            B2[(T) & 1][5] = ds_read128<IMMB(T,5)>(_bb);                                      \
            B2[(T) & 1][6] = ds_read128<IMMB(T,6)>(_bb);                                      \
            B2[(T) & 1][7] = ds_read128<IMMB(T,7)>(_bb); } while (0)

        #define KSTEP(T) do {                                                                 \
            if ((T) <= 16) asm volatile("s_waitcnt lgkmcnt(8) vmcnt(4)" ::: "memory");        \
            else           asm volatile("s_waitcnt lgkmcnt(0) vmcnt(0)" ::: "memory");        \
            __builtin_amdgcn_sched_barrier(0);                                                \
            __builtin_amdgcn_s_setprio(1);                                                    \
            { const int _q = (T) & 1;                                                         \
              _Pragma("unroll")                                                               \
              for (int _m = 0; _m < 4; ++_m)                                                  \
                _Pragma("unroll")                                                             \
                for (int _n = 0; _n < 8; ++_n)                                                \
                    acc[_m][_n] = MFMA16_(A2[_q][_m], B2[_q][_n], acc[_m][_n]); }             \
            __builtin_amdgcn_s_setprio(0);                                                    \
            __builtin_amdgcn_sched_barrier(0);                                                \
            if ((T) + 2 <= 17) { PRELB((T) + 2); PRELA((T) + 2); }                            \
        } while (0)

        PRELA(0); PRELB(0); PRELA(1); PRELB(1);

        KSTEP(0);  KSTEP(1);  KSTEP(2);  KSTEP(3);  KSTEP(4);  KSTEP(5);
        KSTEP(6);  KSTEP(7);  KSTEP(8);  KSTEP(9);  KSTEP(10); KSTEP(11);
        KSTEP(12); KSTEP(13); KSTEP(14); KSTEP(15); KSTEP(16); KSTEP(17);

        asm volatile("s_waitcnt lgkmcnt(0) vmcnt(0)" ::: "memory");
        __builtin_amdgcn_sched_barrier(0);
    } else {
        // fallback: plain loop straight from w, same geometry/layout
        #pragma unroll
        for (int step = 0; step < 18; ++step) {
            const int s = step >> 1, h = step & 1;
            const int kh = s / 3, kw = s % 3;
            bf16x8 A[4], B[8];
            #pragma unroll
            for (int m = 0; m < 4; ++m)
                #pragma unroll
                for (int j = 0; j < 8; ++j)
                    A[m][j] = (__bf16)w[(mb + m * 16 + l15) * 576 +
                                        (h * 32 + lg * 8 + j) * 9 + s];
            #pragma unroll
            for (int n = 0; n < 8; ++n) {
                int col = n * 16 + l15 + kw;
                B[n] = *(const bf16x8*)(smem + (waveR + kh) * ROW_STRIDE + h * H_STRIDE +
                                        (col >> 4) * BLK_STRIDE + lg * 256 + (col & 15) * 16);
            }
            #pragma unroll
            for (int m = 0; m < 4; ++m)
                #pragma unroll
                for (int n = 0; n < 8; ++n)
                    acc[m][n] = MFMA16_(A[m], B[n], acc[m][n]);
        }
    }

    // ---- epilogue: +bias, min over this wave's 64 couts, shfl, cross-waveM via pmin
    {
        float pm[8];
        #pragma unroll
        for (int n = 0; n < 8; ++n) pm[n] = 1e30f;
        #pragma unroll
        for (int m = 0; m < 4; ++m) {
            #pragma unroll
            for (int r = 0; r < 4; ++r) {
                float bv = bias[mb + m * 16 + lg * 4 + r];    // cout
                #pragma unroll
                for (int n = 0; n < 8; ++n)
                    pm[n] = fminf(pm[n], acc[m][n][r] + bv);
            }
        }
        #pragma unroll
        for (int n = 0; n < 8; ++n) {
            pm[n] = fminf(pm[n], __shfl_xor(pm[n], 16, 64));
            pm[n] = fminf(pm[n], __shfl_xor(pm[n], 32, 64));
        }
        if (lg == 0) {
            #pragma unroll
            for (int n = 0; n < 8; ++n)
                pmin[(waveR * 2 + waveM) * 128 + n * 16 + l15] = pm[n];
        }
    }
    __syncthreads();
    {
        const int hh  = tid >> 7;            // 0..1
        const int col = tid & 127;
        if (col < WO) {
            float v = fminf(pmin[(hh * 2 + 0) * 128 + col], pmin[(hh * 2 + 1) * 128 + col]);
            v = tanhf(tanhf(v));
            out[((size_t)b * HO + R + hh) * WO + col] = v;
        }
    }
}

extern "C" void kernel_launch(void* const* d_in, const int* in_sizes, int n_in,
                              void* d_out, int out_size, void* d_ws, size_t ws_size,
                              hipStream_t stream) {
    const float* x    = (const float*)d_in[0];
    const float* w    = (const float*)d_in[1];
    const float* bias = (const float*)d_in[2];
    float* out = (float*)d_out;

    const size_t ws_needed = (size_t)18 * 4 * 128 * 16;   // 147456 B
    if (ws_size >= ws_needed) {
        unsigned short* wsb = (unsigned short*)d_ws;
        wreorder_3556<<<288, 256, 0, stream>>>(w, wsb);
        conv_min_tanh_3556<true><<<NB * 63, 256, 0, stream>>>(x, w, bias, (const unsigned char*)wsb, out);
    } else {
        conv_min_tanh_3556<false><<<NB * 63, 256, 0, stream>>>(x, w, bias, nullptr, out);
    }
}

// Round 20
// 66.980 us; speedup vs baseline: 1.3099x; 1.0187x over previous
//
#include <hip/hip_runtime.h>
#include <hip/hip_bf16.h>

#define CIN  64
#define HH   128
#define WW   128
#define COUT 128
#define HO   126
#define WO   126
#define NB   32
#define HW   (HH * WW)

typedef __bf16 bf16x8 __attribute__((ext_vector_type(8)));
typedef float f32x4 __attribute__((ext_vector_type(4)));

// ws2 granule layout: [step(18)=(s,h)][kg(4)][cout(128)] 16B granules
// granule(step,kg,cout)[j] = bf16(w[cout][ci = 32h + 8kg + j][s])
__global__ void wreorder_3556(const float* __restrict__ w, unsigned short* __restrict__ ws2) {
    int e = blockIdx.x * 256 + threadIdx.x;      // 0..73727
    if (e >= 73728) return;
    int j = e & 7, cout = (e >> 3) & 127, kg = (e >> 10) & 3, h = (e >> 12) & 1, s = e >> 13;
    __bf16 v = (__bf16)w[cout * 576 + (h * 32 + kg * 8 + j) * 9 + s];
    ws2[e] = __builtin_bit_cast(unsigned short, v);
}

// LDS x layout: [row(4)][h(2)][colblk(9)][kg(4)][c(16)] 16B granules, block stride 1040B
//   addr(row,h,col,kg) = row*18720 + h*9360 + (col>>4)*1040 + kg*256 + (col&15)*16
#define ROW_STRIDE 18720
#define H_STRIDE   9360
#define BLK_STRIDE 1040
#define PM_OFF  74880
#define SMEM_BYTES (74880 + 2048)   // 76928 -> 2 blocks/CU

__device__ __forceinline__ unsigned lds_addr(const void* p) {
    return (unsigned)(unsigned long long)(const __attribute__((address_space(3))) unsigned char*)p;
}
template<int OFF>
__device__ __forceinline__ bf16x8 ds_read128(unsigned base) {
    bf16x8 d;
    asm volatile("ds_read_b128 %0, %1 offset:%c2" : "=v"(d) : "v"(base), "i"(OFF));
    return d;
}
template<int OFF>
__device__ __forceinline__ bf16x8 glob_load128(const unsigned char* sbase, unsigned voff) {
    bf16x8 d;
    asm volatile("global_load_dwordx4 %0, %1, %2 offset:%c3"
                 : "=v"(d) : "v"(voff), "s"(sbase), "i"(OFF));
    return d;
}

#define MFMA16_(a, b, c) __builtin_amdgcn_mfma_f32_16x16x32_bf16((a), (b), (c), 0, 0, 0)

// step T: s = T>>1, h = T&1; kh = s/3, kw = s%3
#define S_(T)  ((T) >> 1)
#define H_(T)  ((T) & 1)
#define KH_(T) (S_(T) / 3)
#define KW_(T) (S_(T) % 3)
#define IMMB(T, N) (KH_(T) * ROW_STRIDE + H_(T) * H_STRIDE + (N) * BLK_STRIDE)

template<bool USE_WS>
__global__ __launch_bounds__(256, 2)
void conv_min_tanh_3556(const float* __restrict__ x, const float* __restrict__ w,
                        const float* __restrict__ bias,
                        const unsigned char* __restrict__ wsr_b,
                        float* __restrict__ out) {
    __shared__ __align__(16) unsigned char smem[SMEM_BYTES];
    float* pmin = (float*)(smem + PM_OFF);

    // XCD-chunked bijective swizzle (2016 = 8 * 252)
    const int bid = blockIdx.x;
    const int blk = (bid & 7) * 252 + (bid >> 3);
    const int b   = blk / 63;
    const int R   = (blk - b * 63) * 2;      // output rows R, R+1; input rows R..R+3

    const int tid  = threadIdx.x;
    const int lane = tid & 63;
    const int wid  = tid >> 6;               // 0..3
    const int l15 = lane & 15;
    const int lg  = lane >> 4;               // 0..3 (16-lane group)
    const int waveM = wid & 1;               // cout half (0/1)
    const int waveR = wid >> 1;              // output row within pair (0/1)
    const int mb = waveM * 64;

    // ---- A register pipeline state + early prefetch (hidden under staging)
    bf16x8 A2[2][4];   // [slot][m]  32 VGPR
    bf16x8 B2[2][8];   // [slot][n]  64 VGPR
    const unsigned voffA = (unsigned)(lg * 2048 + (mb + l15) * 16);

    #define PRELA(T) do { const unsigned _va = voffA + (T) * 8192u;                       \
        A2[(T) & 1][0] = glob_load128<0>(wsr_b, _va);                                     \
        A2[(T) & 1][1] = glob_load128<256>(wsr_b, _va);                                   \
        A2[(T) & 1][2] = glob_load128<512>(wsr_b, _va);                                   \
        A2[(T) & 1][3] = glob_load128<768>(wsr_b, _va); } while (0)

    if constexpr (USE_WS) { PRELA(0); PRELA(1); }

    // ---- stage x rows R..R+3, vectorized f32x4 loads (4 items/thread), block-16-col layout
    {
        const float* xb = x + (size_t)b * CIN * HW + (size_t)R * WW;
        #pragma unroll
        for (int it = 0; it < 4; ++it) {
            int item = it * 256 + tid;          // 0..1023
            int col4 = item & 31;               // 4-col group
            int cg   = (item >> 5) & 7;         // ci-granule: h = cg>>2, kg = cg&3
            int row  = item >> 8;               // 0..3
            const float* src = xb + (size_t)(cg * 8) * HW + (size_t)row * WW + col4 * 4;
            f32x4 v[8];
            #pragma unroll
            for (int j = 0; j < 8; ++j) v[j] = *(const f32x4*)(src + (size_t)j * HW);
            const int wb0 = row * ROW_STRIDE + (cg >> 2) * H_STRIDE + (cg & 3) * 256;
            #pragma unroll
            for (int c = 0; c < 4; ++c) {
                int col = col4 * 4 + c;
                union { unsigned short us[8]; int4 i4; } p;
                #pragma unroll
                for (int j = 0; j < 8; ++j) {
                    __bf16 t = (__bf16)v[j][c];
                    p.us[j] = __builtin_bit_cast(unsigned short, t);
                }
                *(int4*)(smem + wb0 + (col >> 4) * BLK_STRIDE + (col & 15) * 16) = p.i4;
            }
        }
        if (tid < 64) {   // zero-pad block 8 (cols 128,129) for all rows/h/kg
            int row = tid >> 4, hh = (tid >> 3) & 1, kg = (tid >> 1) & 3, cz = tid & 1;
            int4 z = {0, 0, 0, 0};
            *(int4*)(smem + row * ROW_STRIDE + hh * H_STRIDE + 8 * BLK_STRIDE + kg * 256 + cz * 16) = z;
        }
    }
    __syncthreads();   // drains vmcnt(0): A2 slots 0,1 resident past here

    f32x4 acc[4][8] = {};   // [m][n] : 64 cout x 128 col, 16x16 tiles

    if constexpr (USE_WS) {
        // B bases per kw: lane col' = l15 + kw; carry into next 16-col block
        unsigned baseB[3];
        #pragma unroll
        for (int kw = 0; kw < 3; ++kw) {
            int cp = l15 + kw;
            baseB[kw] = lds_addr(smem) + (unsigned)(waveR * ROW_STRIDE + lg * 256 +
                        (cp >> 4) * BLK_STRIDE + (cp & 15) * 16);
        }

        #define PRELB(T) do { const unsigned _bb = baseB[KW_(T)];                             \
            B2[(T) & 1][0] = ds_read128<IMMB(T,0)>(_bb);                                      \
            B2[(T) & 1][1] = ds_read128<IMMB(T,1)>(_bb);                                      \
            B2[(T) & 1][2] = ds_read128<IMMB(T,2)>(_bb);                                      \
            B2[(T) & 1][3] = ds_read128<IMMB(T,3)>(_bb);                                      \
            B2[(T) & 1][4] = ds_read128<IMMB(T,4)>(_bb);                                      \
            B2[(T) & 1][5] = ds_read128<IMMB(T,5)>(_bb);                                      \
            B2[(T) & 1][6] = ds_read128<IMMB(T,6)>(_bb);                                      \
            B2[(T) & 1][7] = ds_read128<IMMB(T,7)>(_bb); } while (0)

        #define KSTEP(T) do {                                                                 \
            if ((T) <= 16) asm volatile("s_waitcnt lgkmcnt(8) vmcnt(4)" ::: "memory");        \
            else           asm volatile("s_waitcnt lgkmcnt(0) vmcnt(0)" ::: "memory");        \
            __builtin_amdgcn_sched_barrier(0);                                                \
            __builtin_amdgcn_s_setprio(1);                                                    \
            { const int _q = (T) & 1;                                                         \
              _Pragma("unroll")                                                               \
              for (int _m = 0; _m < 4; ++_m)                                                  \
                _Pragma("unroll")                                                             \
                for (int _n = 0; _n < 8; ++_n)                                                \
                    acc[_m][_n] = MFMA16_(A2[_q][_m], B2[_q][_n], acc[_m][_n]); }             \
            __builtin_amdgcn_s_setprio(0);                                                    \
            __builtin_amdgcn_sched_barrier(0);                                                \
            if ((T) + 2 <= 17) { PRELB((T) + 2); PRELA((T) + 2); }                            \
        } while (0)

        PRELB(0); PRELB(1);

        KSTEP(0);  KSTEP(1);  KSTEP(2);  KSTEP(3);  KSTEP(4);  KSTEP(5);
        KSTEP(6);  KSTEP(7);  KSTEP(8);  KSTEP(9);  KSTEP(10); KSTEP(11);
        KSTEP(12); KSTEP(13); KSTEP(14); KSTEP(15); KSTEP(16); KSTEP(17);

        asm volatile("s_waitcnt lgkmcnt(0) vmcnt(0)" ::: "memory");
        __builtin_amdgcn_sched_barrier(0);
    } else {
        // fallback: plain loop straight from w, same geometry/layout
        #pragma unroll
        for (int step = 0; step < 18; ++step) {
            const int s = step >> 1, h = step & 1;
            const int kh = s / 3, kw = s % 3;
            bf16x8 A[4], B[8];
            #pragma unroll
            for (int m = 0; m < 4; ++m)
                #pragma unroll
                for (int j = 0; j < 8; ++j)
                    A[m][j] = (__bf16)w[(mb + m * 16 + l15) * 576 +
                                        (h * 32 + lg * 8 + j) * 9 + s];
            #pragma unroll
            for (int n = 0; n < 8; ++n) {
                int col = n * 16 + l15 + kw;
                B[n] = *(const bf16x8*)(smem + (waveR + kh) * ROW_STRIDE + h * H_STRIDE +
                                        (col >> 4) * BLK_STRIDE + lg * 256 + (col & 15) * 16);
            }
            #pragma unroll
            for (int m = 0; m < 4; ++m)
                #pragma unroll
                for (int n = 0; n < 8; ++n)
                    acc[m][n] = MFMA16_(A[m], B[n], acc[m][n]);
        }
    }

    // ---- epilogue: +bias, min over this wave's 64 couts, shfl, cross-waveM via pmin
    {
        float pm[8];
        #pragma unroll
        for (int n = 0; n < 8; ++n) pm[n] = 1e30f;
        #pragma unroll
        for (int m = 0; m < 4; ++m) {
            #pragma unroll
            for (int r = 0; r < 4; ++r) {
                float bv = bias[mb + m * 16 + lg * 4 + r];    // cout
                #pragma unroll
                for (int n = 0; n < 8; ++n)
                    pm[n] = fminf(pm[n], acc[m][n][r] + bv);
            }
        }
        #pragma unroll
        for (int n = 0; n < 8; ++n) {
            pm[n] = fminf(pm[n], __shfl_xor(pm[n], 16, 64));
            pm[n] = fminf(pm[n], __shfl_xor(pm[n], 32, 64));
        }
        if (lg == 0) {
            #pragma unroll
            for (int n = 0; n < 8; ++n)
                pmin[(waveR * 2 + waveM) * 128 + n * 16 + l15] = pm[n];
        }
    }
    __syncthreads();
    {
        const int hh  = tid >> 7;            // 0..1
        const int col = tid & 127;
        if (col < WO) {
            float v = fminf(pmin[(hh * 2 + 0) * 128 + col], pmin[(hh * 2 + 1) * 128 + col]);
            v = tanhf(tanhf(v));
            out[((size_t)b * HO + R + hh) * WO + col] = v;
        }
    }
}

extern "C" void kernel_launch(void* const* d_in, const int* in_sizes, int n_in,
                              void* d_out, int out_size, void* d_ws, size_t ws_size,
                              hipStream_t stream) {
    const float* x    = (const float*)d_in[0];
    const float* w    = (const float*)d_in[1];
    const float* bias = (const float*)d_in[2];
    float* out = (float*)d_out;

    const size_t ws_needed = (size_t)18 * 4 * 128 * 16;   // 147456 B
    if (ws_size >= ws_needed) {
        unsigned short* wsb = (unsigned short*)d_ws;
        wreorder_3556<<<288, 256, 0, stream>>>(w, wsb);
        conv_min_tanh_3556<true><<<NB * 63, 256, 0, stream>>>(x, w, bias, (const unsigned char*)wsb, out);
    } else {
        conv_min_tanh_3556<false><<<NB * 63, 256, 0, stream>>>(x, w, bias, nullptr, out);
    }
}

// Round 21
// 66.276 us; speedup vs baseline: 1.3238x; 1.0106x over previous
//
#include <hip/hip_runtime.h>
#include <hip/hip_bf16.h>

#define CIN  64
#define HH   128
#define WW   128
#define COUT 128
#define HO   126
#define WO   126
#define NB   32
#define HW   (HH * WW)

typedef __bf16 bf16x8 __attribute__((ext_vector_type(8)));
typedef float f32x4 __attribute__((ext_vector_type(4)));

// ws2 granule layout: [step(18)=(s,h)][kg(4)][cout(128)] 16B granules
// granule(step,kg,cout)[j] = bf16(w[cout][ci = 32h + 8kg + j][s])
__global__ void wreorder_3556(const float* __restrict__ w, unsigned short* __restrict__ ws2) {
    int e = blockIdx.x * 256 + threadIdx.x;      // 0..73727
    if (e >= 73728) return;
    int j = e & 7, cout = (e >> 3) & 127, kg = (e >> 10) & 3, h = (e >> 12) & 1, s = e >> 13;
    __bf16 v = (__bf16)w[cout * 576 + (h * 32 + kg * 8 + j) * 9 + s];
    ws2[e] = __builtin_bit_cast(unsigned short, v);
}

// LDS x layout: [row(4)][h(2)][colblk(9)][kg(4)][c(16)] 16B granules, block stride 1040B
//   addr(row,h,col,kg) = row*18720 + h*9360 + (col>>4)*1040 + kg*256 + (col&15)*16
#define ROW_STRIDE 18720
#define H_STRIDE   9360
#define BLK_STRIDE 1040
#define PM_OFF  74880
#define SMEM_BYTES (74880 + 2048)   // 76928 -> 2 blocks/CU

__device__ __forceinline__ unsigned lds_addr(const void* p) {
    return (unsigned)(unsigned long long)(const __attribute__((address_space(3))) unsigned char*)p;
}
template<int OFF>
__device__ __forceinline__ bf16x8 ds_read128(unsigned base) {
    bf16x8 d;
    asm volatile("ds_read_b128 %0, %1 offset:%c2" : "=v"(d) : "v"(base), "i"(OFF));
    return d;
}
template<int OFF>
__device__ __forceinline__ bf16x8 glob_load128(const unsigned char* sbase, unsigned voff) {
    bf16x8 d;
    asm volatile("global_load_dwordx4 %0, %1, %2 offset:%c3"
                 : "=v"(d) : "v"(voff), "s"(sbase), "i"(OFF));
    return d;
}

#define MFMA16_(a, b, c) __builtin_amdgcn_mfma_f32_16x16x32_bf16((a), (b), (c), 0, 0, 0)
#define SBAR() __builtin_amdgcn_sched_barrier(0)

// step T: s = T>>1, h = T&1; kh = s/3, kw = s%3
#define S_(T)  ((T) >> 1)
#define H_(T)  ((T) & 1)
#define KH_(T) (S_(T) / 3)
#define KW_(T) (S_(T) % 3)
#define IMMB(T, N) (KH_(T) * ROW_STRIDE + H_(T) * H_STRIDE + (N) * BLK_STRIDE)

template<bool USE_WS>
__global__ __launch_bounds__(256, 2)
void conv_min_tanh_3556(const float* __restrict__ x, const float* __restrict__ w,
                        const float* __restrict__ bias,
                        const unsigned char* __restrict__ wsr_b,
                        float* __restrict__ out) {
    __shared__ __align__(16) unsigned char smem[SMEM_BYTES];
    float* pmin = (float*)(smem + PM_OFF);

    // XCD-chunked bijective swizzle (2016 = 8 * 252)
    const int bid = blockIdx.x;
    const int blk = (bid & 7) * 252 + (bid >> 3);
    const int b   = blk / 63;
    const int R   = (blk - b * 63) * 2;      // output rows R, R+1; input rows R..R+3

    const int tid  = threadIdx.x;
    const int lane = tid & 63;
    const int wid  = tid >> 6;               // 0..3
    const int l15 = lane & 15;
    const int lg  = lane >> 4;               // 0..3 (16-lane group)
    const int waveM = wid & 1;               // cout half (0/1)
    const int waveR = wid >> 1;              // output row within pair (0/1)
    const int mb = waveM * 64;

    // ---- A register pipeline state + early prefetch (hidden under staging)
    bf16x8 A2[2][4];   // [slot][m]  32 VGPR
    bf16x8 B2[2][8];   // [slot][n]  64 VGPR
    const unsigned voffA = (unsigned)(lg * 2048 + (mb + l15) * 16);

    #define PRELA(T) do { const unsigned _va = voffA + (T) * 8192u;                       \
        A2[(T) & 1][0] = glob_load128<0>(wsr_b, _va);                                     \
        A2[(T) & 1][1] = glob_load128<256>(wsr_b, _va);                                   \
        A2[(T) & 1][2] = glob_load128<512>(wsr_b, _va);                                   \
        A2[(T) & 1][3] = glob_load128<768>(wsr_b, _va); } while (0)

    if constexpr (USE_WS) { PRELA(0); PRELA(1); }

    // ---- stage x rows R..R+3, vectorized f32x4 loads (4 items/thread), block-16-col layout
    {
        const float* xb = x + (size_t)b * CIN * HW + (size_t)R * WW;
        #pragma unroll
        for (int it = 0; it < 4; ++it) {
            int item = it * 256 + tid;          // 0..1023
            int col4 = item & 31;               // 4-col group
            int cg   = (item >> 5) & 7;         // ci-granule: h = cg>>2, kg = cg&3
            int row  = item >> 8;               // 0..3
            const float* src = xb + (size_t)(cg * 8) * HW + (size_t)row * WW + col4 * 4;
            f32x4 v[8];
            #pragma unroll
            for (int j = 0; j < 8; ++j) v[j] = *(const f32x4*)(src + (size_t)j * HW);
            const int wb0 = row * ROW_STRIDE + (cg >> 2) * H_STRIDE + (cg & 3) * 256;
            #pragma unroll
            for (int c = 0; c < 4; ++c) {
                int col = col4 * 4 + c;
                union { unsigned short us[8]; int4 i4; } p;
                #pragma unroll
                for (int j = 0; j < 8; ++j) {
                    __bf16 t = (__bf16)v[j][c];
                    p.us[j] = __builtin_bit_cast(unsigned short, t);
                }
                *(int4*)(smem + wb0 + (col >> 4) * BLK_STRIDE + (col & 15) * 16) = p.i4;
            }
        }
        if (tid < 64) {   // zero-pad block 8 (cols 128,129) for all rows/h/kg
            int row = tid >> 4, hh = (tid >> 3) & 1, kg = (tid >> 1) & 3, cz = tid & 1;
            int4 z = {0, 0, 0, 0};
            *(int4*)(smem + row * ROW_STRIDE + hh * H_STRIDE + 8 * BLK_STRIDE + kg * 256 + cz * 16) = z;
        }
    }
    __syncthreads();   // drains vmcnt(0): A2 slots 0,1 resident past here

    f32x4 acc[4][8] = {};   // [m][n] : 64 cout x 128 col, 16x16 tiles

    if constexpr (USE_WS) {
        // B bases per kw: lane col' = l15 + kw; carry into next 16-col block
        unsigned baseB[3];
        #pragma unroll
        for (int kw = 0; kw < 3; ++kw) {
            int cp = l15 + kw;
            baseB[kw] = lds_addr(smem) + (unsigned)(waveR * ROW_STRIDE + lg * 256 +
                        (cp >> 4) * BLK_STRIDE + (cp & 15) * 16);
        }

        // reload one n-pair of B for step T (2 ds_reads into slot T&1)
        #define PRELB2(T, P) do { const unsigned _bb = baseB[KW_(T)];                         \
            B2[(T) & 1][2*(P)]   = ds_read128<IMMB(T, 2*(P))>(_bb);                           \
            B2[(T) & 1][2*(P)+1] = ds_read128<IMMB(T, 2*(P)+1)>(_bb); } while (0)

        // 8 MFMAs: n-pair P (n = 2P, 2P+1) across all 4 m — consumes B2[q][2P..2P+1]
        #define MF_NPAIR(Q, P) do {                                                           \
            _Pragma("unroll")                                                                 \
            for (int _m = 0; _m < 4; ++_m) {                                                  \
                acc[_m][2*(P)]   = MFMA16_(A2[Q][_m], B2[Q][2*(P)],   acc[_m][2*(P)]);        \
                acc[_m][2*(P)+1] = MFMA16_(A2[Q][_m], B2[Q][2*(P)+1], acc[_m][2*(P)+1]);      \
            } } while (0)

        // Interleaved step: {8 MFMA}{2 ds}{8 MFMA}{2 ds}{8 MFMA}{2 ds}{8 MFMA}{2 ds + 4 glob}
        #define KSTEP(T) do {                                                                 \
            if ((T) <= 16) asm volatile("s_waitcnt lgkmcnt(8) vmcnt(4)" ::: "memory");        \
            else           asm volatile("s_waitcnt lgkmcnt(0) vmcnt(0)" ::: "memory");        \
            SBAR();                                                                           \
            __builtin_amdgcn_s_setprio(1);                                                    \
            { const int _q = (T) & 1;                                                         \
              MF_NPAIR(_q, 0); SBAR();                                                        \
              if ((T) + 2 <= 17) { PRELB2((T) + 2, 0); } SBAR();                              \
              MF_NPAIR(_q, 1); SBAR();                                                        \
              if ((T) + 2 <= 17) { PRELB2((T) + 2, 1); } SBAR();                              \
              MF_NPAIR(_q, 2); SBAR();                                                        \
              if ((T) + 2 <= 17) { PRELB2((T) + 2, 2); } SBAR();                              \
              MF_NPAIR(_q, 3); SBAR();                                                        \
              if ((T) + 2 <= 17) { PRELB2((T) + 2, 3); PRELA((T) + 2); } }                    \
            __builtin_amdgcn_s_setprio(0);                                                    \
            SBAR();                                                                           \
        } while (0)

        // prologue B loads (steps 0,1)
        #define PRELB_ALL(T) do { PRELB2(T,0); PRELB2(T,1); PRELB2(T,2); PRELB2(T,3); } while (0)
        PRELB_ALL(0); PRELB_ALL(1);

        KSTEP(0);  KSTEP(1);  KSTEP(2);  KSTEP(3);  KSTEP(4);  KSTEP(5);
        KSTEP(6);  KSTEP(7);  KSTEP(8);  KSTEP(9);  KSTEP(10); KSTEP(11);
        KSTEP(12); KSTEP(13); KSTEP(14); KSTEP(15); KSTEP(16); KSTEP(17);

        asm volatile("s_waitcnt lgkmcnt(0) vmcnt(0)" ::: "memory");
        SBAR();
    } else {
        // fallback: plain loop straight from w, same geometry/layout
        #pragma unroll
        for (int step = 0; step < 18; ++step) {
            const int s = step >> 1, h = step & 1;
            const int kh = s / 3, kw = s % 3;
            bf16x8 A[4], B[8];
            #pragma unroll
            for (int m = 0; m < 4; ++m)
                #pragma unroll
                for (int j = 0; j < 8; ++j)
                    A[m][j] = (__bf16)w[(mb + m * 16 + l15) * 576 +
                                        (h * 32 + lg * 8 + j) * 9 + s];
            #pragma unroll
            for (int n = 0; n < 8; ++n) {
                int col = n * 16 + l15 + kw;
                B[n] = *(const bf16x8*)(smem + (waveR + kh) * ROW_STRIDE + h * H_STRIDE +
                                        (col >> 4) * BLK_STRIDE + lg * 256 + (col & 15) * 16);
            }
            #pragma unroll
            for (int m = 0; m < 4; ++m)
                #pragma unroll
                for (int n = 0; n < 8; ++n)
                    acc[m][n] = MFMA16_(A[m], B[n], acc[m][n]);
        }
    }

    // ---- epilogue: +bias, min over this wave's 64 couts, shfl, cross-waveM via pmin
    {
        float pm[8];
        #pragma unroll
        for (int n = 0; n < 8; ++n) pm[n] = 1e30f;
        #pragma unroll
        for (int m = 0; m < 4; ++m) {
            #pragma unroll
            for (int r = 0; r < 4; ++r) {
                float bv = bias[mb + m * 16 + lg * 4 + r];    // cout
                #pragma unroll
                for (int n = 0; n < 8; ++n)
                    pm[n] = fminf(pm[n], acc[m][n][r] + bv);
            }
        }
        #pragma unroll
        for (int n = 0; n < 8; ++n) {
            pm[n] = fminf(pm[n], __shfl_xor(pm[n], 16, 64));
            pm[n] = fminf(pm[n], __shfl_xor(pm[n], 32, 64));
        }
        if (lg == 0) {
            #pragma unroll
            for (int n = 0; n < 8; ++n)
                pmin[(waveR * 2 + waveM) * 128 + n * 16 + l15] = pm[n];
        }
    }
    __syncthreads();
    {
        const int hh  = tid >> 7;            // 0..1
        const int col = tid & 127;
        if (col < WO) {
            float v = fminf(pmin[(hh * 2 + 0) * 128 + col], pmin[(hh * 2 + 1) * 128 + col]);
            v = tanhf(tanhf(v));
            out[((size_t)b * HO + R + hh) * WO + col] = v;
        }
    }
}

extern "C" void kernel_launch(void* const* d_in, const int* in_sizes, int n_in,
                              void* d_out, int out_size, void* d_ws, size_t ws_size,
                              hipStream_t stream) {
    const float* x    = (const float*)d_in[0];
    const float* w    = (const float*)d_in[1];
    const float* bias = (const float*)d_in[2];
    float* out = (float*)d_out;

    const size_t ws_needed = (size_t)18 * 4 * 128 * 16;   // 147456 B
    if (ws_size >= ws_needed) {
        unsigned short* wsb = (unsigned short*)d_ws;
        wreorder_3556<<<288, 256, 0, stream>>>(w, wsb);
        conv_min_tanh_3556<true><<<NB * 63, 256, 0, stream>>>(x, w, bias, (const unsigned char*)wsb, out);
    } else {
        conv_min_tanh_3556<false><<<NB * 63, 256, 0, stream>>>(x, w, bias, nullptr, out);
    }
}